// Round 2
// baseline (130.214 us; speedup 1.0000x reference)
//
#include <hip/hip_runtime.h>
#include <hip/hip_bf16.h>
#include <cstdint>
#include <cstddef>

// GraphConvSparse: out = relu(adj @ (x @ W)), adj = dense 0/1 symmetric
// adjacency with SET semantics (duplicate edges count once).
// N=16384, E=524288, D=128.
//
// Pipeline:
//  1. memset deg[16384] (64 KB)
//  2. fill: per-row neighbor slots (CAP=192) via atomicAdd cursor (multiset)
//  3. gemm: h = x @ W, fp32 compute, bf16 output (4 MB -> fits per-XCD L2)
//  4. agg: wave-per-row; dedup (shfl + ballot-compact in LDS); gather bf16
//          rows of h; fp32 accumulate; relu; store.
//
// ws layout: [0,64KB) deg | [64KB, +12MB) cols | then h2 (bf16 pairs, 4 MB)

constexpr int NN  = 16384;
constexpr int D   = 128;
constexpr int CAP = 192;   // Poisson(64) deg incl dups; P(>192) ~ e^-70. safe.

constexpr size_t DEG_BYTES  = (size_t)NN * 4;              // 64 KB
constexpr size_t COLS_BYTES = (size_t)NN * CAP * 4;        // 12 MB

__device__ inline unsigned short f2bf(float f) {
    union { float f; unsigned int u; } x; x.f = f;
    unsigned int u = x.u;
    unsigned int r = (u + 0x7fffu + ((u >> 16) & 1u)) >> 16;   // RTNE
    return (unsigned short)r;
}

// ---------------- kernel 1: fill per-row neighbor slots (multiset) --------
__global__ __launch_bounds__(256) void fill_kernel(
    const int* __restrict__ ei, int E,
    unsigned int* __restrict__ deg, int* __restrict__ cols) {
    int e = blockIdx.x * 256 + threadIdx.x;
    if (e >= E) return;
    int u = ei[e];         // row 0 of (2,E)
    int v = ei[E + e];     // row 1 of (2,E)
    unsigned int s = atomicAdd(&deg[u], 1u);
    if (s < CAP) cols[(size_t)u * CAP + s] = v;
    unsigned int t = atomicAdd(&deg[v], 1u);
    if (t < CAP) cols[(size_t)v * CAP + t] = u;
}

// ---------------- kernel 2: h = x @ W (fp32 compute, bf16 out) ------------
// 64x64 tile per block, 256 threads, 4x4 register tile.
__global__ __launch_bounds__(256) void gemm_kernel(
    const float* __restrict__ x, const float* __restrict__ w,
    unsigned int* __restrict__ h2) {
    __shared__ float xt[D][64];   // x tile transposed [k][row]
    __shared__ float wl[D][64];   // w tile natural    [k][col]
    const int tid  = threadIdx.x;
    const int rb   = blockIdx.x >> 1;
    const int cb   = blockIdx.x & 1;
    const int row0 = rb * 64, col0 = cb * 64;

    for (int i = tid; i < 64 * (D / 4); i += 256) {
        int r = i >> 5, k4 = i & 31;
        float4 xv = *(const float4*)&x[(size_t)(row0 + r) * D + (k4 << 2)];
        xt[(k4 << 2) + 0][r] = xv.x;
        xt[(k4 << 2) + 1][r] = xv.y;
        xt[(k4 << 2) + 2][r] = xv.z;
        xt[(k4 << 2) + 3][r] = xv.w;
    }
    for (int i = tid; i < D * (64 / 4); i += 256) {
        int k = i >> 4, c4 = i & 15;
        *(float4*)&wl[k][c4 << 2] =
            *(const float4*)&w[(size_t)k * D + col0 + (c4 << 2)];
    }
    __syncthreads();

    const int cg = tid & 15, rg = tid >> 4;
    const int c0 = cg << 2, r0 = rg << 2;
    float acc[4][4] = {};
    #pragma unroll 4
    for (int k = 0; k < D; ++k) {
        float4 xv = *(float4*)&xt[k][r0];
        float4 wv = *(float4*)&wl[k][c0];
        const float xr[4] = {xv.x, xv.y, xv.z, xv.w};
        const float wc[4] = {wv.x, wv.y, wv.z, wv.w};
        #pragma unroll
        for (int r = 0; r < 4; ++r)
            #pragma unroll
            for (int c = 0; c < 4; ++c)
                acc[r][c] = fmaf(xr[r], wc[c], acc[r][c]);
    }
    #pragma unroll
    for (int r = 0; r < 4; ++r) {
        unsigned int p0 = (unsigned int)f2bf(acc[r][0]) |
                          ((unsigned int)f2bf(acc[r][1]) << 16);
        unsigned int p1 = (unsigned int)f2bf(acc[r][2]) |
                          ((unsigned int)f2bf(acc[r][3]) << 16);
        uint2 v; v.x = p0; v.y = p1;
        *(uint2*)&h2[(size_t)(row0 + r0 + r) * 64 + ((col0 + c0) >> 1)] = v;
    }
}

// ---------------- kernel 3: out[i] = relu(sum_{j in set(adj[i])} h[j]) ----
// one wave per row; 4 rows per 256-thread block.
// dedup: within-chunk via shfl broadcasts, cross-chunk vs compacted LDS list,
// ballot-compaction. lane handles bf16 dims (2*lane, 2*lane+1).
__global__ __launch_bounds__(256) void agg_kernel(
    const unsigned int* __restrict__ deg, const int* __restrict__ cols,
    const unsigned int* __restrict__ h2, float* __restrict__ out) {
    __shared__ int Lc[4][CAP];
    const int wave = threadIdx.x >> 6, lane = threadIdx.x & 63;
    const int row  = blockIdx.x * 4 + wave;

    int d = (int)deg[row];
    if (d > CAP) d = CAP;
    const int* crow = cols + (size_t)row * CAP;
    int* L = Lc[wave];

    int nd = 0;
    for (int base = 0; base < d; base += 64) {
        int p = base + lane;
        int j = (p < d) ? crow[p] : -1;
        bool keep = (p < d);
        // within-chunk: match against earlier lanes
        #pragma unroll
        for (int q = 0; q < 63; ++q) {
            int vq = __shfl(j, q);
            if (q < lane && vq == j) keep = false;
        }
        // cross-chunk: match against compacted prefix (broadcast reads)
        for (int q = 0; q < nd; ++q) {
            if (L[q] == j) keep = false;
        }
        unsigned long long m = __ballot(keep);
        int pre = (int)__popcll(m & ((1ull << (unsigned)lane) - 1ull));
        if (keep) L[nd + pre] = j;
        nd += (int)__popcll(m);
        asm volatile("s_waitcnt lgkmcnt(0)" ::: "memory");
    }

    float a0 = 0.f, a1 = 0.f;
    int i = 0;
    for (; i + 4 <= nd; i += 4) {
        int j0 = L[i], j1 = L[i + 1], j2 = L[i + 2], j3 = L[i + 3];
        unsigned int u0 = h2[(unsigned)j0 * 64u + lane];
        unsigned int u1 = h2[(unsigned)j1 * 64u + lane];
        unsigned int u2 = h2[(unsigned)j2 * 64u + lane];
        unsigned int u3 = h2[(unsigned)j3 * 64u + lane];
        a0 += __uint_as_float(u0 << 16); a1 += __uint_as_float(u0 & 0xffff0000u);
        a0 += __uint_as_float(u1 << 16); a1 += __uint_as_float(u1 & 0xffff0000u);
        a0 += __uint_as_float(u2 << 16); a1 += __uint_as_float(u2 & 0xffff0000u);
        a0 += __uint_as_float(u3 << 16); a1 += __uint_as_float(u3 & 0xffff0000u);
    }
    for (; i < nd; ++i) {
        unsigned int u0 = h2[(unsigned)L[i] * 64u + lane];
        a0 += __uint_as_float(u0 << 16); a1 += __uint_as_float(u0 & 0xffff0000u);
    }
    float2 r; r.x = fmaxf(a0, 0.f); r.y = fmaxf(a1, 0.f);
    *(float2*)&out[(size_t)row * D + lane * 2] = r;
}

extern "C" void kernel_launch(void* const* d_in, const int* in_sizes, int n_in,
                              void* d_out, int out_size, void* d_ws, size_t ws_size,
                              hipStream_t stream) {
    const float* x  = (const float*)d_in[0];
    const int*   ei = (const int*)d_in[1];     // (2,E) int32
    const float* w  = (const float*)d_in[3];   // d_in[2] = num_nodes scalar
    float* out = (float*)d_out;

    unsigned int* deg  = (unsigned int*)d_ws;
    int*          cols = (int*)((char*)d_ws + DEG_BYTES);
    unsigned int* h2   = (unsigned int*)((char*)d_ws + DEG_BYTES + COLS_BYTES);

    const int E = in_sizes[1] / 2;

    hipMemsetAsync(deg, 0, DEG_BYTES, stream);
    fill_kernel<<<(E + 255) / 256, 256, 0, stream>>>(ei, E, deg, cols);
    gemm_kernel<<<512, 256, 0, stream>>>(x, w, h2);
    agg_kernel<<<NN / 4, 256, 0, stream>>>(deg, cols, h2, out);
}

// Round 3
// 71.535 us; speedup vs baseline: 1.8203x; 1.8203x over previous
//
#include <hip/hip_runtime.h>
#include <hip/hip_bf16.h>
#include <cstdint>
#include <cstddef>

// GraphConvSparse: out = relu(adj @ (x @ W)), adj = dense 0/1 symmetric
// adjacency with SET semantics (duplicate edges count once).
// N=16384, E=524288, D=128.
//
// Pipeline:
//  1. memset bucket cursors (2 KB)
//  2. fused kernel: partition blocks (edges -> 512 per-bucket entry lists,
//     bucket = row>>5, entry = lrow<<14|col) + gemm blocks (h = x@W, fp32
//     compute, bf16-pair output, 4 MB -> L2-resident)
//  3. agg: one block per bucket; 32-row x 16384-bit adjacency bitmask in LDS
//     (atomicOr = dedup); wave-per-row scan/compact/gather/accumulate/relu.
//
// ws layout: [0,2KB) cursor | [64KB, +4MB) h2 | [64KB+4MB, +6MB) entries

constexpr int NN   = 16384;
constexpr int D    = 128;
constexpr int NB   = 512;            // buckets
constexpr int RPB  = 32;             // rows per bucket
constexpr int WPR  = NN / 32;        // 512 mask words per row
constexpr int CAPB = 3072;           // entries capacity per bucket (mean 2048, sigma 45)
constexpr int EPB  = 4096;           // edges per partition block
constexpr int LCAP = 320;            // per-wave neighbor list capacity

constexpr size_t CUR_BYTES = (size_t)NB * 4;              // 2 KB
constexpr size_t H2_OFF    = 65536;
constexpr size_t ENT_OFF   = H2_OFF + (size_t)NN * 64 * 4; // h2 = N x 64 u32 (4 MB)

__device__ inline unsigned short f2bf(float f) {
    union { float f; unsigned int u; } x; x.f = f;
    unsigned int u = x.u;
    unsigned int r = (u + 0x7fffu + ((u >> 16) & 1u)) >> 16;   // RTNE
    return (unsigned short)r;
}

// ---------------- fused: partition (blocks [0,nPart)) + gemm (rest) -------
__global__ __launch_bounds__(256) void part_gemm_kernel(
    const int* __restrict__ ei, int E, int nPart,
    unsigned int* __restrict__ cursor, unsigned int* __restrict__ entries,
    const float* __restrict__ x, const float* __restrict__ w,
    unsigned int* __restrict__ h2) {
    __shared__ __align__(16) char smem[65536];
    const int tid = threadIdx.x;

    if ((int)blockIdx.x < nPart) {
        // ---------------- partition ----------------
        int* cnt  = (int*)smem;          // [512]
        int* base = cnt + NB;            // [512]
        int* loff = base + NB;           // [512]
        for (int i = tid; i < NB; i += 256) { cnt[i] = 0; loff[i] = 0; }
        __syncthreads();

        const int e0 = blockIdx.x * EPB;
        int u[16], v[16];
        #pragma unroll
        for (int k = 0; k < 16; ++k) {
            int p = e0 + k * 256 + tid;
            if (p < E) {
                u[k] = ei[p];
                v[k] = ei[E + p];
                atomicAdd(&cnt[u[k] >> 5], 1);
                atomicAdd(&cnt[v[k] >> 5], 1);
            } else { u[k] = -1; v[k] = -1; }
        }
        __syncthreads();
        for (int b = tid; b < NB; b += 256)
            base[b] = cnt[b] ? (int)atomicAdd(&cursor[b], (unsigned)cnt[b]) : 0;
        __syncthreads();
        #pragma unroll
        for (int k = 0; k < 16; ++k) {
            if (u[k] >= 0) {
                int b1 = u[k] >> 5;
                int o1 = base[b1] + atomicAdd(&loff[b1], 1);
                if (o1 < CAPB)
                    entries[(size_t)b1 * CAPB + o1] =
                        ((unsigned)(u[k] & 31) << 14) | (unsigned)v[k];
                int b2 = v[k] >> 5;
                int o2 = base[b2] + atomicAdd(&loff[b2], 1);
                if (o2 < CAPB)
                    entries[(size_t)b2 * CAPB + o2] =
                        ((unsigned)(v[k] & 31) << 14) | (unsigned)u[k];
            }
        }
        return;
    }

    // ---------------- gemm: 64x64 tile, 4x4 register tile ----------------
    float (*xt)[64] = (float(*)[64])smem;            // [128][64] 32 KB
    float (*wl)[64] = (float(*)[64])(smem + 32768);  // [128][64] 32 KB
    const int gb   = (int)blockIdx.x - nPart;
    const int rb   = gb >> 1, cb = gb & 1;
    const int row0 = rb * 64, col0 = cb * 64;

    for (int i = tid; i < 64 * (D / 4); i += 256) {
        int r = i >> 5, k4 = i & 31;
        float4 xv = *(const float4*)&x[(size_t)(row0 + r) * D + (k4 << 2)];
        xt[(k4 << 2) + 0][r] = xv.x;
        xt[(k4 << 2) + 1][r] = xv.y;
        xt[(k4 << 2) + 2][r] = xv.z;
        xt[(k4 << 2) + 3][r] = xv.w;
    }
    for (int i = tid; i < D * (64 / 4); i += 256) {
        int k = i >> 4, c4 = i & 15;
        *(float4*)&wl[k][c4 << 2] =
            *(const float4*)&w[(size_t)k * D + col0 + (c4 << 2)];
    }
    __syncthreads();

    const int cg = tid & 15, rg = tid >> 4;
    const int c0 = cg << 2, r0 = rg << 2;
    float acc[4][4] = {};
    #pragma unroll 4
    for (int k = 0; k < D; ++k) {
        float4 xv = *(float4*)&xt[k][r0];
        float4 wv = *(float4*)&wl[k][c0];
        const float xr[4] = {xv.x, xv.y, xv.z, xv.w};
        const float wc[4] = {wv.x, wv.y, wv.z, wv.w};
        #pragma unroll
        for (int r = 0; r < 4; ++r)
            #pragma unroll
            for (int c = 0; c < 4; ++c)
                acc[r][c] = fmaf(xr[r], wc[c], acc[r][c]);
    }
    #pragma unroll
    for (int r = 0; r < 4; ++r) {
        unsigned int p0 = (unsigned int)f2bf(acc[r][0]) |
                          ((unsigned int)f2bf(acc[r][1]) << 16);
        unsigned int p1 = (unsigned int)f2bf(acc[r][2]) |
                          ((unsigned int)f2bf(acc[r][3]) << 16);
        uint2 vv; vv.x = p0; vv.y = p1;
        *(uint2*)&h2[(size_t)(row0 + r0 + r) * 64 + ((col0 + c0) >> 1)] = vv;
    }
}

// ---------------- agg: one block per bucket ----------------
__global__ __launch_bounds__(512) void agg_kernel(
    const unsigned int* __restrict__ cursor,
    const unsigned int* __restrict__ entries,
    const unsigned int* __restrict__ h2, float* __restrict__ out) {
    __shared__ unsigned int mask[RPB * WPR];   // 64 KB bitmask: 32 rows x 16384 bits
    __shared__ int Lw[8][LCAP];                // 10 KB per-wave neighbor lists
    const int b = blockIdx.x, tid = threadIdx.x;
    const int wave = tid >> 6, lane = tid & 63;

    for (int i = tid; i < RPB * WPR; i += 512) mask[i] = 0;
    __syncthreads();

    int n = (int)cursor[b];
    if (n > CAPB) n = CAPB;
    const unsigned int* ent = entries + (size_t)b * CAPB;
    for (int i = tid; i < n; i += 512) {
        unsigned int e = ent[i];
        unsigned int lr = e >> 14, c = e & 16383u;
        atomicOr(&mask[lr * WPR + (c >> 5)], 1u << (c & 31u));
    }
    __syncthreads();

    const int r0 = b * RPB;
    for (int rr = wave; rr < RPB; rr += 8) {
        const unsigned int* mrow = &mask[rr * WPR];
        unsigned int wbits[8];
        int c = 0;
        #pragma unroll
        for (int k = 0; k < 8; ++k) {         // stride-64 words: conflict-free
            wbits[k] = mrow[lane + k * 64];
            c += __popc(wbits[k]);
        }
        // exclusive scan of per-lane counts
        int inc = c;
        #pragma unroll
        for (int dd = 1; dd < 64; dd <<= 1) {
            int t = __shfl_up(inc, dd);
            if (lane >= dd) inc += t;
        }
        int p = inc - c;                       // exclusive prefix
        int total = __shfl(inc, 63);
        if (total > LCAP) total = LCAP;
        int* L = Lw[wave];
        #pragma unroll
        for (int k = 0; k < 8; ++k) {
            unsigned int m = wbits[k];
            int cbase = (lane + k * 64) << 5;
            while (m) {
                int bt = __builtin_ctz(m);
                m &= m - 1;
                if (p < LCAP) L[p] = cbase + bt;
                ++p;
            }
        }
        asm volatile("s_waitcnt lgkmcnt(0)" ::: "memory");  // wave-lockstep LDS visibility

        float a0 = 0.f, a1 = 0.f;
        int i = 0;
        for (; i + 8 <= total; i += 8) {
            unsigned int u0 = h2[(unsigned)L[i + 0] * 64u + lane];
            unsigned int u1 = h2[(unsigned)L[i + 1] * 64u + lane];
            unsigned int u2 = h2[(unsigned)L[i + 2] * 64u + lane];
            unsigned int u3 = h2[(unsigned)L[i + 3] * 64u + lane];
            unsigned int u4 = h2[(unsigned)L[i + 4] * 64u + lane];
            unsigned int u5 = h2[(unsigned)L[i + 5] * 64u + lane];
            unsigned int u6 = h2[(unsigned)L[i + 6] * 64u + lane];
            unsigned int u7 = h2[(unsigned)L[i + 7] * 64u + lane];
            a0 += __uint_as_float(u0 << 16); a1 += __uint_as_float(u0 & 0xffff0000u);
            a0 += __uint_as_float(u1 << 16); a1 += __uint_as_float(u1 & 0xffff0000u);
            a0 += __uint_as_float(u2 << 16); a1 += __uint_as_float(u2 & 0xffff0000u);
            a0 += __uint_as_float(u3 << 16); a1 += __uint_as_float(u3 & 0xffff0000u);
            a0 += __uint_as_float(u4 << 16); a1 += __uint_as_float(u4 & 0xffff0000u);
            a0 += __uint_as_float(u5 << 16); a1 += __uint_as_float(u5 & 0xffff0000u);
            a0 += __uint_as_float(u6 << 16); a1 += __uint_as_float(u6 & 0xffff0000u);
            a0 += __uint_as_float(u7 << 16); a1 += __uint_as_float(u7 & 0xffff0000u);
        }
        for (; i < total; ++i) {
            unsigned int u0 = h2[(unsigned)L[i] * 64u + lane];
            a0 += __uint_as_float(u0 << 16); a1 += __uint_as_float(u0 & 0xffff0000u);
        }
        float2 r; r.x = fmaxf(a0, 0.f); r.y = fmaxf(a1, 0.f);
        *(float2*)&out[(size_t)(r0 + rr) * D + lane * 2] = r;
    }
}

extern "C" void kernel_launch(void* const* d_in, const int* in_sizes, int n_in,
                              void* d_out, int out_size, void* d_ws, size_t ws_size,
                              hipStream_t stream) {
    const float* x  = (const float*)d_in[0];
    const int*   ei = (const int*)d_in[1];     // (2,E) int32
    const float* w  = (const float*)d_in[3];   // d_in[2] = num_nodes scalar
    float* out = (float*)d_out;

    unsigned int* cursor  = (unsigned int*)d_ws;
    unsigned int* h2      = (unsigned int*)((char*)d_ws + H2_OFF);
    unsigned int* entries = (unsigned int*)((char*)d_ws + ENT_OFF);

    const int E = in_sizes[1] / 2;
    const int nPart = (E + EPB - 1) / EPB;     // 128

    hipMemsetAsync(cursor, 0, CUR_BYTES, stream);
    part_gemm_kernel<<<nPart + 512, 256, 0, stream>>>(
        ei, E, nPart, cursor, entries, x, w, h2);
    agg_kernel<<<NB, 512, 0, stream>>>(cursor, entries, h2, out);
}

// Round 4
// 71.451 us; speedup vs baseline: 1.8224x; 1.0012x over previous
//
#include <hip/hip_runtime.h>
#include <hip/hip_bf16.h>
#include <cstdint>
#include <cstddef>

// GraphConvSparse: out = relu(adj @ (x @ W)), adj = dense 0/1 symmetric
// adjacency with SET semantics (duplicate edges count once).
// N=16384, E=524288, D=128.
//
// Pipeline:
//  1. zero_kernel: clear 512 bucket cursors (hipMemsetAsync's fillBuffer
//     kernel cost 42 us/replay in the graph -- own 1-block kernel instead)
//  2. fused kernel: partition blocks (edges -> 512 per-bucket entry lists,
//     bucket = row>>5, entry = lrow<<14|col) + gemm blocks (h = x@W, fp32
//     compute, bf16-pair output, 4 MB -> L2-resident)
//  3. agg: one block per bucket; 32-row x 16384-bit adjacency bitmask in LDS
//     (atomicOr = dedup); wave-per-row scan/compact/gather/accumulate/relu.
//
// ws layout: [0,2KB) cursor | [64KB, +4MB) h2 | [64KB+4MB, +6MB) entries

constexpr int NN   = 16384;
constexpr int D    = 128;
constexpr int NB   = 512;            // buckets
constexpr int RPB  = 32;             // rows per bucket
constexpr int WPR  = NN / 32;        // 512 mask words per row
constexpr int CAPB = 3072;           // entries capacity per bucket (mean 2048)
constexpr int EPB  = 4096;           // edges per partition block
constexpr int LCAP = 320;            // per-wave neighbor list capacity

constexpr size_t H2_OFF  = 65536;
constexpr size_t ENT_OFF = H2_OFF + (size_t)NN * 64 * 4;   // h2 = N x 64 u32 (4 MB)

__device__ inline unsigned short f2bf(float f) {
    union { float f; unsigned int u; } x; x.f = f;
    unsigned int u = x.u;
    unsigned int r = (u + 0x7fffu + ((u >> 16) & 1u)) >> 16;   // RTNE
    return (unsigned short)r;
}

// ---------------- kernel 0: zero the bucket cursors ----------------
__global__ __launch_bounds__(512) void zero_kernel(unsigned int* __restrict__ cursor) {
    cursor[threadIdx.x] = 0u;
}

// ---------------- fused: partition (blocks [0,nPart)) + gemm (rest) -------
__global__ __launch_bounds__(256) void part_gemm_kernel(
    const int* __restrict__ ei, int E, int nPart,
    unsigned int* __restrict__ cursor, unsigned int* __restrict__ entries,
    const float* __restrict__ x, const float* __restrict__ w,
    unsigned int* __restrict__ h2) {
    __shared__ __align__(16) char smem[65536];
    const int tid = threadIdx.x;

    if ((int)blockIdx.x < nPart) {
        // ---------------- partition ----------------
        int* cnt  = (int*)smem;          // [512]
        int* base = cnt + NB;            // [512]
        int* loff = base + NB;           // [512]
        for (int i = tid; i < NB; i += 256) { cnt[i] = 0; loff[i] = 0; }
        __syncthreads();

        const int e0 = blockIdx.x * EPB;
        int u[16], v[16];
        #pragma unroll
        for (int k = 0; k < 16; ++k) {
            int p = e0 + k * 256 + tid;
            if (p < E) {
                u[k] = ei[p];
                v[k] = ei[E + p];
                atomicAdd(&cnt[u[k] >> 5], 1);
                atomicAdd(&cnt[v[k] >> 5], 1);
            } else { u[k] = -1; v[k] = -1; }
        }
        __syncthreads();
        for (int b = tid; b < NB; b += 256)
            base[b] = cnt[b] ? (int)atomicAdd(&cursor[b], (unsigned)cnt[b]) : 0;
        __syncthreads();
        #pragma unroll
        for (int k = 0; k < 16; ++k) {
            if (u[k] >= 0) {
                int b1 = u[k] >> 5;
                int o1 = base[b1] + atomicAdd(&loff[b1], 1);
                if (o1 < CAPB)
                    entries[(size_t)b1 * CAPB + o1] =
                        ((unsigned)(u[k] & 31) << 14) | (unsigned)v[k];
                int b2 = v[k] >> 5;
                int o2 = base[b2] + atomicAdd(&loff[b2], 1);
                if (o2 < CAPB)
                    entries[(size_t)b2 * CAPB + o2] =
                        ((unsigned)(v[k] & 31) << 14) | (unsigned)u[k];
            }
        }
        return;
    }

    // ---------------- gemm: 64x64 tile, 4x4 register tile ----------------
    float (*xt)[64] = (float(*)[64])smem;            // [128][64] 32 KB
    float (*wl)[64] = (float(*)[64])(smem + 32768);  // [128][64] 32 KB
    const int gb   = (int)blockIdx.x - nPart;
    const int rb   = gb >> 1, cb = gb & 1;
    const int row0 = rb * 64, col0 = cb * 64;

    for (int i = tid; i < 64 * (D / 4); i += 256) {
        int r = i >> 5, k4 = i & 31;
        float4 xv = *(const float4*)&x[(size_t)(row0 + r) * D + (k4 << 2)];
        xt[(k4 << 2) + 0][r] = xv.x;
        xt[(k4 << 2) + 1][r] = xv.y;
        xt[(k4 << 2) + 2][r] = xv.z;
        xt[(k4 << 2) + 3][r] = xv.w;
    }
    for (int i = tid; i < D * (64 / 4); i += 256) {
        int k = i >> 4, c4 = i & 15;
        *(float4*)&wl[k][c4 << 2] =
            *(const float4*)&w[(size_t)k * D + col0 + (c4 << 2)];
    }
    __syncthreads();

    const int cg = tid & 15, rg = tid >> 4;
    const int c0 = cg << 2, r0 = rg << 2;
    float acc[4][4] = {};
    #pragma unroll 4
    for (int k = 0; k < D; ++k) {
        float4 xv = *(float4*)&xt[k][r0];
        float4 wv = *(float4*)&wl[k][c0];
        const float xr[4] = {xv.x, xv.y, xv.z, xv.w};
        const float wc[4] = {wv.x, wv.y, wv.z, wv.w};
        #pragma unroll
        for (int r = 0; r < 4; ++r)
            #pragma unroll
            for (int c = 0; c < 4; ++c)
                acc[r][c] = fmaf(xr[r], wc[c], acc[r][c]);
    }
    #pragma unroll
    for (int r = 0; r < 4; ++r) {
        unsigned int p0 = (unsigned int)f2bf(acc[r][0]) |
                          ((unsigned int)f2bf(acc[r][1]) << 16);
        unsigned int p1 = (unsigned int)f2bf(acc[r][2]) |
                          ((unsigned int)f2bf(acc[r][3]) << 16);
        uint2 vv; vv.x = p0; vv.y = p1;
        *(uint2*)&h2[(size_t)(row0 + r0 + r) * 64 + ((col0 + c0) >> 1)] = vv;
    }
}

// ---------------- agg: one block per bucket ----------------
__global__ __launch_bounds__(512) void agg_kernel(
    const unsigned int* __restrict__ cursor,
    const unsigned int* __restrict__ entries,
    const unsigned int* __restrict__ h2, float* __restrict__ out) {
    __shared__ unsigned int mask[RPB * WPR];   // 64 KB bitmask: 32 rows x 16384 bits
    __shared__ int Lw[8][LCAP];                // 10 KB per-wave neighbor lists
    const int b = blockIdx.x, tid = threadIdx.x;
    const int wave = tid >> 6, lane = tid & 63;

    for (int i = tid; i < RPB * WPR; i += 512) mask[i] = 0;
    __syncthreads();

    int n = (int)cursor[b];
    if (n > CAPB) n = CAPB;
    const unsigned int* ent = entries + (size_t)b * CAPB;
    for (int i = tid; i < n; i += 512) {
        unsigned int e = ent[i];
        unsigned int lr = e >> 14, c = e & 16383u;
        atomicOr(&mask[lr * WPR + (c >> 5)], 1u << (c & 31u));
    }
    __syncthreads();

    const int r0 = b * RPB;
    for (int rr = wave; rr < RPB; rr += 8) {
        const unsigned int* mrow = &mask[rr * WPR];
        unsigned int wbits[8];
        int c = 0;
        #pragma unroll
        for (int k = 0; k < 8; ++k) {         // stride-64 words: conflict-free
            wbits[k] = mrow[lane + k * 64];
            c += __popc(wbits[k]);
        }
        // exclusive scan of per-lane counts
        int inc = c;
        #pragma unroll
        for (int dd = 1; dd < 64; dd <<= 1) {
            int t = __shfl_up(inc, dd);
            if (lane >= dd) inc += t;
        }
        int p = inc - c;                       // exclusive prefix
        int total = __shfl(inc, 63);
        if (total > LCAP) total = LCAP;
        int* L = Lw[wave];
        #pragma unroll
        for (int k = 0; k < 8; ++k) {
            unsigned int m = wbits[k];
            int cbase = (lane + k * 64) << 5;
            while (m) {
                int bt = __builtin_ctz(m);
                m &= m - 1;
                if (p < LCAP) L[p] = cbase + bt;
                ++p;
            }
        }
        asm volatile("s_waitcnt lgkmcnt(0)" ::: "memory");  // wave-lockstep LDS visibility

        float a0 = 0.f, a1 = 0.f;
        int i = 0;
        for (; i + 8 <= total; i += 8) {
            unsigned int u0 = h2[(unsigned)L[i + 0] * 64u + lane];
            unsigned int u1 = h2[(unsigned)L[i + 1] * 64u + lane];
            unsigned int u2 = h2[(unsigned)L[i + 2] * 64u + lane];
            unsigned int u3 = h2[(unsigned)L[i + 3] * 64u + lane];
            unsigned int u4 = h2[(unsigned)L[i + 4] * 64u + lane];
            unsigned int u5 = h2[(unsigned)L[i + 5] * 64u + lane];
            unsigned int u6 = h2[(unsigned)L[i + 6] * 64u + lane];
            unsigned int u7 = h2[(unsigned)L[i + 7] * 64u + lane];
            a0 += __uint_as_float(u0 << 16); a1 += __uint_as_float(u0 & 0xffff0000u);
            a0 += __uint_as_float(u1 << 16); a1 += __uint_as_float(u1 & 0xffff0000u);
            a0 += __uint_as_float(u2 << 16); a1 += __uint_as_float(u2 & 0xffff0000u);
            a0 += __uint_as_float(u3 << 16); a1 += __uint_as_float(u3 & 0xffff0000u);
            a0 += __uint_as_float(u4 << 16); a1 += __uint_as_float(u4 & 0xffff0000u);
            a0 += __uint_as_float(u5 << 16); a1 += __uint_as_float(u5 & 0xffff0000u);
            a0 += __uint_as_float(u6 << 16); a1 += __uint_as_float(u6 & 0xffff0000u);
            a0 += __uint_as_float(u7 << 16); a1 += __uint_as_float(u7 & 0xffff0000u);
        }
        for (; i < total; ++i) {
            unsigned int u0 = h2[(unsigned)L[i] * 64u + lane];
            a0 += __uint_as_float(u0 << 16); a1 += __uint_as_float(u0 & 0xffff0000u);
        }
        float2 r; r.x = fmaxf(a0, 0.f); r.y = fmaxf(a1, 0.f);
        *(float2*)&out[(size_t)(r0 + rr) * D + lane * 2] = r;
    }
}

extern "C" void kernel_launch(void* const* d_in, const int* in_sizes, int n_in,
                              void* d_out, int out_size, void* d_ws, size_t ws_size,
                              hipStream_t stream) {
    const float* x  = (const float*)d_in[0];
    const int*   ei = (const int*)d_in[1];     // (2,E) int32
    const float* w  = (const float*)d_in[3];   // d_in[2] = num_nodes scalar
    float* out = (float*)d_out;

    unsigned int* cursor  = (unsigned int*)d_ws;
    unsigned int* h2      = (unsigned int*)((char*)d_ws + H2_OFF);
    unsigned int* entries = (unsigned int*)((char*)d_ws + ENT_OFF);

    const int E = in_sizes[1] / 2;
    const int nPart = (E + EPB - 1) / EPB;     // 128

    zero_kernel<<<1, NB, 0, stream>>>(cursor);
    part_gemm_kernel<<<nPart + 512, 256, 0, stream>>>(
        ei, E, nPart, cursor, entries, x, w, h2);
    agg_kernel<<<NB, 512, 0, stream>>>(cursor, entries, h2, out);
}

// Round 5
// 64.940 us; speedup vs baseline: 2.0051x; 1.1003x over previous
//
#include <hip/hip_runtime.h>
#include <hip/hip_bf16.h>
#include <cstdint>
#include <cstddef>

// GraphConvSparse: out = relu(adj @ (x @ W)), adj = dense 0/1 symmetric
// adjacency with SET semantics (duplicate edges count once).
// N=16384, E=524288, D=128.
//
// NOTE (R4 finding): the harness re-poisons the 256 MiB d_ws at ~41 us per
// replay cycle inside the timed path; our kernels are ~30 us of the ~71 us
// total. This round shrinks our side: 2 dispatches, no global atomics.
//
// Pipeline:
//  1. part_gemm: partition blocks write edges into deterministic per-
//     (bucket, partition-block) segments of 48 slots (LDS cursor only,
//     single pass) + counts array; gemm blocks compute h = x@W (fp32
//     compute, bf16-pair output, 4 MB -> L2-resident).
//  2. agg: one block per bucket (32 rows); replay segments into a 64 KB LDS
//     bitmask (atomicOr = dedup); wave-per-row scan/compact/gather/relu.
//
// ws layout: [0,256KB) counts | [256KB,+4MB) h2 | [+4MB, +12.6MB) entries

constexpr int NN   = 16384;
constexpr int D    = 128;
constexpr int NB   = 512;            // buckets
constexpr int RPB  = 32;             // rows per bucket
constexpr int WPR  = NN / 32;        // 512 mask words per row
constexpr int EPB  = 4096;           // edges per partition block
constexpr int SLOT = 48;             // slots per (bucket, pblock) segment
constexpr int LCAP = 320;            // per-wave neighbor list capacity

constexpr size_t H2_OFF  = 262144;                          // counts: 256 KB
constexpr size_t ENT_OFF = H2_OFF + (size_t)NN * 64 * 4;    // h2: 4 MB

__device__ inline unsigned short f2bf(float f) {
    union { float f; unsigned int u; } x; x.f = f;
    unsigned int u = x.u;
    unsigned int r = (u + 0x7fffu + ((u >> 16) & 1u)) >> 16;   // RTNE
    return (unsigned short)r;
}

// ---------------- fused: partition (blocks [0,nPart)) + gemm (rest) -------
__global__ __launch_bounds__(256) void part_gemm_kernel(
    const int* __restrict__ ei, int E, int nPart,
    unsigned int* __restrict__ counts, unsigned int* __restrict__ entries,
    const float* __restrict__ x, const float* __restrict__ w,
    unsigned int* __restrict__ h2) {
    __shared__ __align__(16) char smem[65536];
    const int tid = threadIdx.x;

    if ((int)blockIdx.x < nPart) {
        // ------------- partition: single pass, LDS cursors only -----------
        int* loff = (int*)smem;          // [512]
        for (int i = tid; i < NB; i += 256) loff[i] = 0;
        __syncthreads();

        const int e0 = blockIdx.x * EPB;
        const int pb = blockIdx.x;
        #pragma unroll
        for (int k = 0; k < 16; ++k) {
            int p = e0 + k * 256 + tid;
            if (p < E) {
                int u = ei[p];
                int v = ei[E + p];
                int b1 = u >> 5;
                int o1 = atomicAdd(&loff[b1], 1);
                if (o1 < SLOT)
                    entries[((size_t)b1 * nPart + pb) * SLOT + o1] =
                        ((unsigned)(u & 31) << 14) | (unsigned)v;
                int b2 = v >> 5;
                int o2 = atomicAdd(&loff[b2], 1);
                if (o2 < SLOT)
                    entries[((size_t)b2 * nPart + pb) * SLOT + o2] =
                        ((unsigned)(v & 31) << 14) | (unsigned)u;
            }
        }
        __syncthreads();
        for (int b = tid; b < NB; b += 256) {
            int c = loff[b]; if (c > SLOT) c = SLOT;
            counts[(size_t)b * nPart + pb] = (unsigned)c;
        }
        return;
    }

    // ---------------- gemm: 64x64 tile, 4x4 register tile ----------------
    float (*xt)[64] = (float(*)[64])smem;            // [128][64] 32 KB
    float (*wl)[64] = (float(*)[64])(smem + 32768);  // [128][64] 32 KB
    const int gb   = (int)blockIdx.x - nPart;
    const int rb   = gb >> 1, cb = gb & 1;
    const int row0 = rb * 64, col0 = cb * 64;

    for (int i = tid; i < 64 * (D / 4); i += 256) {
        int r = i >> 5, k4 = i & 31;
        float4 xv = *(const float4*)&x[(size_t)(row0 + r) * D + (k4 << 2)];
        xt[(k4 << 2) + 0][r] = xv.x;
        xt[(k4 << 2) + 1][r] = xv.y;
        xt[(k4 << 2) + 2][r] = xv.z;
        xt[(k4 << 2) + 3][r] = xv.w;
    }
    for (int i = tid; i < D * (64 / 4); i += 256) {
        int k = i >> 4, c4 = i & 15;
        *(float4*)&wl[k][c4 << 2] =
            *(const float4*)&w[(size_t)k * D + col0 + (c4 << 2)];
    }
    __syncthreads();

    const int cg = tid & 15, rg = tid >> 4;
    const int c0 = cg << 2, r0 = rg << 2;
    float acc[4][4] = {};
    #pragma unroll 4
    for (int k = 0; k < D; ++k) {
        float4 xv = *(float4*)&xt[k][r0];
        float4 wv = *(float4*)&wl[k][c0];
        const float xr[4] = {xv.x, xv.y, xv.z, xv.w};
        const float wc[4] = {wv.x, wv.y, wv.z, wv.w};
        #pragma unroll
        for (int r = 0; r < 4; ++r)
            #pragma unroll
            for (int c = 0; c < 4; ++c)
                acc[r][c] = fmaf(xr[r], wc[c], acc[r][c]);
    }
    #pragma unroll
    for (int r = 0; r < 4; ++r) {
        unsigned int p0 = (unsigned int)f2bf(acc[r][0]) |
                          ((unsigned int)f2bf(acc[r][1]) << 16);
        unsigned int p1 = (unsigned int)f2bf(acc[r][2]) |
                          ((unsigned int)f2bf(acc[r][3]) << 16);
        uint2 vv; vv.x = p0; vv.y = p1;
        *(uint2*)&h2[(size_t)(row0 + r0 + r) * 64 + ((col0 + c0) >> 1)] = vv;
    }
}

// ---------------- agg: one block per bucket ----------------
__global__ __launch_bounds__(512) void agg_kernel(
    const unsigned int* __restrict__ counts, int nPart,
    const unsigned int* __restrict__ entries,
    const unsigned int* __restrict__ h2, float* __restrict__ out) {
    __shared__ unsigned int mask[RPB * WPR];   // 64 KB: 32 rows x 16384 bits
    __shared__ int cnt_s[128];
    __shared__ int Lw[8][LCAP];                // 10 KB per-wave lists
    const int b = blockIdx.x, tid = threadIdx.x;
    const int wave = tid >> 6, lane = tid & 63;

    for (int i = tid; i < RPB * WPR; i += 512) mask[i] = 0;
    if (tid < nPart) {
        int c = (int)counts[(size_t)b * nPart + tid];
        if (c > SLOT) c = SLOT;
        cnt_s[tid] = c;
    }
    __syncthreads();

    // replay segments: wave w handles segments [16w, 16w+16)
    const int segs = nPart >> 3;               // per-wave segment count (16)
    for (int s = wave * segs; s < (wave + 1) * segs && s < nPart; ++s) {
        int c = cnt_s[s];
        if (lane < c) {
            unsigned int e = entries[((size_t)b * nPart + s) * SLOT + lane];
            unsigned int lr = e >> 14, cc = e & 16383u;
            atomicOr(&mask[lr * WPR + (cc >> 5)], 1u << (cc & 31u));
        }
    }
    __syncthreads();

    const int r0 = b * RPB;
    for (int rr = wave; rr < RPB; rr += 8) {
        const unsigned int* mrow = &mask[rr * WPR];
        unsigned int wbits[8];
        int c = 0;
        #pragma unroll
        for (int k = 0; k < 8; ++k) {          // stride-64 words: conflict-free
            wbits[k] = mrow[lane + k * 64];
            c += __popc(wbits[k]);
        }
        int inc = c;
        #pragma unroll
        for (int dd = 1; dd < 64; dd <<= 1) {
            int t = __shfl_up(inc, dd);
            if (lane >= dd) inc += t;
        }
        int p = inc - c;                        // exclusive prefix
        int total = __shfl(inc, 63);
        if (total > LCAP) total = LCAP;
        int* L = Lw[wave];
        #pragma unroll
        for (int k = 0; k < 8; ++k) {
            unsigned int m = wbits[k];
            int cbase = (lane + k * 64) << 5;
            while (m) {
                int bt = __builtin_ctz(m);
                m &= m - 1;
                if (p < LCAP) L[p] = cbase + bt;
                ++p;
            }
        }
        asm volatile("s_waitcnt lgkmcnt(0)" ::: "memory");  // wave-lockstep LDS

        float a0 = 0.f, a1 = 0.f;
        int i = 0;
        for (; i + 8 <= total; i += 8) {
            unsigned int u0 = h2[(unsigned)L[i + 0] * 64u + lane];
            unsigned int u1 = h2[(unsigned)L[i + 1] * 64u + lane];
            unsigned int u2 = h2[(unsigned)L[i + 2] * 64u + lane];
            unsigned int u3 = h2[(unsigned)L[i + 3] * 64u + lane];
            unsigned int u4 = h2[(unsigned)L[i + 4] * 64u + lane];
            unsigned int u5 = h2[(unsigned)L[i + 5] * 64u + lane];
            unsigned int u6 = h2[(unsigned)L[i + 6] * 64u + lane];
            unsigned int u7 = h2[(unsigned)L[i + 7] * 64u + lane];
            a0 += __uint_as_float(u0 << 16); a1 += __uint_as_float(u0 & 0xffff0000u);
            a0 += __uint_as_float(u1 << 16); a1 += __uint_as_float(u1 & 0xffff0000u);
            a0 += __uint_as_float(u2 << 16); a1 += __uint_as_float(u2 & 0xffff0000u);
            a0 += __uint_as_float(u3 << 16); a1 += __uint_as_float(u3 & 0xffff0000u);
            a0 += __uint_as_float(u4 << 16); a1 += __uint_as_float(u4 & 0xffff0000u);
            a0 += __uint_as_float(u5 << 16); a1 += __uint_as_float(u5 & 0xffff0000u);
            a0 += __uint_as_float(u6 << 16); a1 += __uint_as_float(u6 & 0xffff0000u);
            a0 += __uint_as_float(u7 << 16); a1 += __uint_as_float(u7 & 0xffff0000u);
        }
        for (; i < total; ++i) {
            unsigned int u0 = h2[(unsigned)L[i] * 64u + lane];
            a0 += __uint_as_float(u0 << 16); a1 += __uint_as_float(u0 & 0xffff0000u);
        }
        float2 r; r.x = fmaxf(a0, 0.f); r.y = fmaxf(a1, 0.f);
        *(float2*)&out[(size_t)(r0 + rr) * D + lane * 2] = r;
    }
}

extern "C" void kernel_launch(void* const* d_in, const int* in_sizes, int n_in,
                              void* d_out, int out_size, void* d_ws, size_t ws_size,
                              hipStream_t stream) {
    const float* x  = (const float*)d_in[0];
    const int*   ei = (const int*)d_in[1];     // (2,E) int32
    const float* w  = (const float*)d_in[3];   // d_in[2] = num_nodes scalar
    float* out = (float*)d_out;

    unsigned int* counts  = (unsigned int*)d_ws;
    unsigned int* h2      = (unsigned int*)((char*)d_ws + H2_OFF);
    unsigned int* entries = (unsigned int*)((char*)d_ws + ENT_OFF);

    const int E = in_sizes[1] / 2;
    const int nPart = (E + EPB - 1) / EPB;     // 128

    part_gemm_kernel<<<nPart + 512, 256, 0, stream>>>(
        ei, E, nPart, counts, entries, x, w, h2);
    agg_kernel<<<NB, 512, 0, stream>>>(counts, nPart, entries, h2, out);
}

// Round 6
// 59.090 us; speedup vs baseline: 2.2037x; 1.0990x over previous
//
#include <hip/hip_runtime.h>
#include <hip/hip_bf16.h>
#include <cstdint>
#include <cstddef>

// GraphConvSparse: out = relu(adj @ (x @ W)), adj = dense 0/1 symmetric
// adjacency with SET semantics (duplicate edges count once).
// N=16384, E=524288, D=128.
//
// NOTE: the harness re-poisons the 256 MiB d_ws (~42 us at HBM peak) inside
// the timed replay path; our kernels are the remaining ~23 us. This round:
// MFMA-ize the gemm (was LDS-bw-bound fp32 VALU at ~10 us).
//
// Pipeline:
//  1. part_gemm: partition blocks (edges -> per-(bucket,pblock) 48-slot
//     segments, LDS cursors only) + gemm blocks (h = x@W via
//     v_mfma_f32_16x16x32_bf16, bf16 operands in swizzled LDS, fp32 acc,
//     bf16 output h2: 4 MB -> L2-resident).
//  2. agg: one block per bucket (32 rows); segments -> 64 KB LDS bitmask
//     (atomicOr = dedup); wave-per-row scan/compact/gather/accumulate/relu.
//
// ws layout: [0,256KB) counts | [256KB,+4MB) h2 | [+4MB, +12.6MB) entries

constexpr int NN   = 16384;
constexpr int D    = 128;
constexpr int NB   = 512;            // buckets
constexpr int RPB  = 32;             // rows per bucket
constexpr int WPR  = NN / 32;        // 512 mask words per row
constexpr int EPB  = 4096;           // edges per partition block
constexpr int SLOT = 48;             // slots per (bucket, pblock) segment
constexpr int LCAP = 320;            // per-wave neighbor list capacity

constexpr size_t H2_OFF  = 262144;                          // counts: 256 KB
constexpr size_t ENT_OFF = H2_OFF + (size_t)NN * 64 * 4;    // h2: 4 MB

typedef short short8 __attribute__((ext_vector_type(8)));   // 8 bf16 (A/B frag)
typedef float f32x4  __attribute__((ext_vector_type(4)));   // C/D frag

__device__ inline unsigned short f2bf(float f) {
    union { float f; unsigned int u; } x; x.f = f;
    unsigned int u = x.u;
    unsigned int r = (u + 0x7fffu + ((u >> 16) & 1u)) >> 16;   // RTNE
    return (unsigned short)r;
}

// ---------------- fused: partition (blocks [0,nPart)) + gemm (rest) -------
__global__ __launch_bounds__(256) void part_gemm_kernel(
    const int* __restrict__ ei, int E, int nPart,
    unsigned int* __restrict__ counts, unsigned int* __restrict__ entries,
    const float* __restrict__ x, const float* __restrict__ w,
    unsigned short* __restrict__ h2s) {
    // union: partition uses first 2 KB; gemm uses 32 KB (x 16K + wT 16K)
    __shared__ __align__(16) char smem[32768];
    const int tid = threadIdx.x;

    if ((int)blockIdx.x < nPart) {
        // ------------- partition: single pass, LDS cursors only -----------
        int* loff = (int*)smem;          // [512]
        for (int i = tid; i < NB; i += 256) loff[i] = 0;
        __syncthreads();

        const int e0 = blockIdx.x * EPB;
        const int pb = blockIdx.x;
        #pragma unroll
        for (int k = 0; k < 16; ++k) {
            int p = e0 + k * 256 + tid;
            if (p < E) {
                int u = ei[p];
                int v = ei[E + p];
                int b1 = u >> 5;
                int o1 = atomicAdd(&loff[b1], 1);
                if (o1 < SLOT)
                    entries[((size_t)b1 * nPart + pb) * SLOT + o1] =
                        ((unsigned)(u & 31) << 14) | (unsigned)v;
                int b2 = v >> 5;
                int o2 = atomicAdd(&loff[b2], 1);
                if (o2 < SLOT)
                    entries[((size_t)b2 * nPart + pb) * SLOT + o2] =
                        ((unsigned)(v & 31) << 14) | (unsigned)u;
            }
        }
        __syncthreads();
        for (int b = tid; b < NB; b += 256) {
            int c = loff[b]; if (c > SLOT) c = SLOT;
            counts[(size_t)b * nPart + pb] = (unsigned)c;
        }
        return;
    }

    // ------------- gemm: 64x64 tile via mfma_f32_16x16x32_bf16 ------------
    // LDS: x_lds [64 rows][128 k] bf16, 16B granules XOR-swizzled (g^=r&7)
    //      wT_lds[64 cols][128 k] bf16, same swizzle    (at byte 16384)
    const int gb   = (int)blockIdx.x - nPart;
    const int rb   = gb >> 1, cb = gb & 1;
    const int row0 = rb * 64, col0 = cb * 64;

    // stage x tile -> bf16, swizzled. 8192 floats / 256 thr = 8 float4 each.
    #pragma unroll
    for (int j = 0; j < 8; ++j) {
        int f  = tid + j * 256;          // float4 index
        int r  = f >> 5, c4 = f & 31;    // row, float4-within-row (k0 = c4*4)
        float4 xv = *(const float4*)&x[(size_t)(row0 + r) * D + (c4 << 2)];
        unsigned int lo = (unsigned)f2bf(xv.x) | ((unsigned)f2bf(xv.y) << 16);
        unsigned int hi = (unsigned)f2bf(xv.z) | ((unsigned)f2bf(xv.w) << 16);
        int g = c4 >> 1;                 // 16B granule = 8 bf16
        int byte = r * 256 + ((g ^ (r & 7)) << 4) + ((c4 & 1) << 3);
        uint2 p; p.x = lo; p.y = hi;
        *(uint2*)&smem[byte] = p;
    }
    // stage W tile transposed -> wT_lds[col][k] bf16, swizzled.
    #pragma unroll
    for (int j = 0; j < 8; ++j) {
        int f  = tid + j * 256;          // float4 index over [128k][16 c4]
        int k  = f >> 4, c4 = f & 15;    // k, col-quad (cols c4*4..+3)
        float4 wv = *(const float4*)&w[(size_t)k * D + col0 + (c4 << 2)];
        const float vals[4] = {wv.x, wv.y, wv.z, wv.w};
        #pragma unroll
        for (int i = 0; i < 4; ++i) {
            int c = (c4 << 2) + i;
            int byte = 16384 + c * 256 + (((k >> 3) ^ (c & 7)) << 4) + ((k & 7) << 1);
            *(unsigned short*)&smem[byte] = f2bf(vals[i]);
        }
    }
    __syncthreads();

    const int lane = tid & 63, wave = tid >> 6;
    const int wr = wave >> 1, wc = wave & 1;     // wave -> 32x32 quadrant
    const int l15 = lane & 15, l4 = lane >> 4;

    f32x4 acc[2][2] = {};
    #pragma unroll
    for (int kk = 0; kk < 4; ++kk) {             // K = 4 x 32
        int g = (kk << 2) + l4;                  // granule for this lane
        short8 a[2], b[2];
        #pragma unroll
        for (int mi = 0; mi < 2; ++mi) {
            int r = wr * 32 + mi * 16 + l15;     // A row
            a[mi] = *(short8*)&smem[r * 256 + ((g ^ (r & 7)) << 4)];
        }
        #pragma unroll
        for (int ni = 0; ni < 2; ++ni) {
            int c = wc * 32 + ni * 16 + l15;     // B col
            b[ni] = *(short8*)&smem[16384 + c * 256 + ((g ^ (c & 7)) << 4)];
        }
        #pragma unroll
        for (int mi = 0; mi < 2; ++mi)
            #pragma unroll
            for (int ni = 0; ni < 2; ++ni)
                acc[mi][ni] = __builtin_amdgcn_mfma_f32_16x16x32_bf16(
                    a[mi], b[ni], acc[mi][ni], 0, 0, 0);
    }

    // epilogue: C/D layout col=lane&15, row=(lane>>4)*4+reg (m89-verified)
    #pragma unroll
    for (int mi = 0; mi < 2; ++mi)
        #pragma unroll
        for (int ni = 0; ni < 2; ++ni) {
            int col = col0 + wc * 32 + ni * 16 + l15;
            #pragma unroll
            for (int reg = 0; reg < 4; ++reg) {
                int row = row0 + wr * 32 + mi * 16 + (l4 << 2) + reg;
                h2s[(size_t)row * D + col] = f2bf(acc[mi][ni][reg]);
            }
        }
}

// ---------------- agg: one block per bucket ----------------
__global__ __launch_bounds__(512) void agg_kernel(
    const unsigned int* __restrict__ counts, int nPart,
    const unsigned int* __restrict__ entries,
    const unsigned int* __restrict__ h2, float* __restrict__ out) {
    __shared__ unsigned int mask[RPB * WPR];   // 64 KB: 32 rows x 16384 bits
    __shared__ int cnt_s[128];
    __shared__ int Lw[8][LCAP];                // 10 KB per-wave lists
    const int b = blockIdx.x, tid = threadIdx.x;
    const int wave = tid >> 6, lane = tid & 63;

    for (int i = tid; i < RPB * WPR; i += 512) mask[i] = 0;
    if (tid < nPart) {
        int c = (int)counts[(size_t)b * nPart + tid];
        if (c > SLOT) c = SLOT;
        cnt_s[tid] = c;
    }
    __syncthreads();

    // replay segments: wave w handles segments [16w, 16w+16)
    const int segs = nPart >> 3;               // per-wave segment count (16)
    for (int s = wave * segs; s < (wave + 1) * segs && s < nPart; ++s) {
        int c = cnt_s[s];
        if (lane < c) {
            unsigned int e = entries[((size_t)b * nPart + s) * SLOT + lane];
            unsigned int lr = e >> 14, cc = e & 16383u;
            atomicOr(&mask[lr * WPR + (cc >> 5)], 1u << (cc & 31u));
        }
    }
    __syncthreads();

    const int r0 = b * RPB;
    for (int rr = wave; rr < RPB; rr += 8) {
        const unsigned int* mrow = &mask[rr * WPR];
        unsigned int wbits[8];
        int c = 0;
        #pragma unroll
        for (int k = 0; k < 8; ++k) {          // stride-64 words: conflict-free
            wbits[k] = mrow[lane + k * 64];
            c += __popc(wbits[k]);
        }
        int inc = c;
        #pragma unroll
        for (int dd = 1; dd < 64; dd <<= 1) {
            int t = __shfl_up(inc, dd);
            if (lane >= dd) inc += t;
        }
        int p = inc - c;                        // exclusive prefix
        int total = __shfl(inc, 63);
        if (total > LCAP) total = LCAP;
        int* L = Lw[wave];
        #pragma unroll
        for (int k = 0; k < 8; ++k) {
            unsigned int m = wbits[k];
            int cbase = (lane + k * 64) << 5;
            while (m) {
                int bt = __builtin_ctz(m);
                m &= m - 1;
                if (p < LCAP) L[p] = cbase + bt;
                ++p;
            }
        }
        asm volatile("s_waitcnt lgkmcnt(0)" ::: "memory");  // wave-lockstep LDS

        float a0 = 0.f, a1 = 0.f;
        int i = 0;
        for (; i + 8 <= total; i += 8) {
            unsigned int u0 = h2[(unsigned)L[i + 0] * 64u + lane];
            unsigned int u1 = h2[(unsigned)L[i + 1] * 64u + lane];
            unsigned int u2 = h2[(unsigned)L[i + 2] * 64u + lane];
            unsigned int u3 = h2[(unsigned)L[i + 3] * 64u + lane];
            unsigned int u4 = h2[(unsigned)L[i + 4] * 64u + lane];
            unsigned int u5 = h2[(unsigned)L[i + 5] * 64u + lane];
            unsigned int u6 = h2[(unsigned)L[i + 6] * 64u + lane];
            unsigned int u7 = h2[(unsigned)L[i + 7] * 64u + lane];
            a0 += __uint_as_float(u0 << 16); a1 += __uint_as_float(u0 & 0xffff0000u);
            a0 += __uint_as_float(u1 << 16); a1 += __uint_as_float(u1 & 0xffff0000u);
            a0 += __uint_as_float(u2 << 16); a1 += __uint_as_float(u2 & 0xffff0000u);
            a0 += __uint_as_float(u3 << 16); a1 += __uint_as_float(u3 & 0xffff0000u);
            a0 += __uint_as_float(u4 << 16); a1 += __uint_as_float(u4 & 0xffff0000u);
            a0 += __uint_as_float(u5 << 16); a1 += __uint_as_float(u5 & 0xffff0000u);
            a0 += __uint_as_float(u6 << 16); a1 += __uint_as_float(u6 & 0xffff0000u);
            a0 += __uint_as_float(u7 << 16); a1 += __uint_as_float(u7 & 0xffff0000u);
        }
        for (; i < total; ++i) {
            unsigned int u0 = h2[(unsigned)L[i] * 64u + lane];
            a0 += __uint_as_float(u0 << 16); a1 += __uint_as_float(u0 & 0xffff0000u);
        }
        float2 r; r.x = fmaxf(a0, 0.f); r.y = fmaxf(a1, 0.f);
        *(float2*)&out[(size_t)(r0 + rr) * D + lane * 2] = r;
    }
}

extern "C" void kernel_launch(void* const* d_in, const int* in_sizes, int n_in,
                              void* d_out, int out_size, void* d_ws, size_t ws_size,
                              hipStream_t stream) {
    const float* x  = (const float*)d_in[0];
    const int*   ei = (const int*)d_in[1];     // (2,E) int32
    const float* w  = (const float*)d_in[3];   // d_in[2] = num_nodes scalar
    float* out = (float*)d_out;

    unsigned int*   counts  = (unsigned int*)d_ws;
    unsigned short* h2s     = (unsigned short*)((char*)d_ws + H2_OFF);
    unsigned int*   h2      = (unsigned int*)((char*)d_ws + H2_OFF);
    unsigned int*   entries = (unsigned int*)((char*)d_ws + ENT_OFF);

    const int E = in_sizes[1] / 2;
    const int nPart = (E + EPB - 1) / EPB;     // 128

    part_gemm_kernel<<<nPart + 512, 256, 0, stream>>>(
        ei, E, nPart, counts, entries, x, w, h2s);
    agg_kernel<<<NB, 512, 0, stream>>>(counts, nPart, entries, h2, out);
}

// Round 7
// 53.653 us; speedup vs baseline: 2.4270x; 1.1013x over previous
//
#include <hip/hip_runtime.h>
#include <hip/hip_bf16.h>
#include <cstdint>
#include <cstddef>

// GraphConvSparse: out = relu(adj @ (x @ W)), adj = dense 0/1 symmetric
// adjacency with SET semantics (duplicate edges count once).
// N=16384, E=524288, D=128.
//
// NOTE: the harness re-poisons the 256 MiB d_ws (~42 us at HBM peak) inside
// the timed replay path; our kernels are the remaining ~16 us.
// R7: partition stages entries in LDS (u16 col + u8 lrow) and flushes one
// CONTIGUOUS coalesced stream per block (kills 2M scattered 4B stores);
// agg zeroes its 64 KB mask with b128 writes.
//
// Pipeline:
//  1. part_gemm: partition blocks (edges -> LDS-staged per-bucket segments,
//     burst-flushed to [pb][bucket][slot] arrays) + gemm blocks (h = x@W via
//     v_mfma_f32_16x16x32_bf16, swizzled bf16 LDS, fp32 acc, bf16 h2 out).
//  2. agg: one block per bucket (32 rows); segments -> 64 KB LDS bitmask
//     (atomicOr = dedup); wave-per-row scan/compact/gather/accumulate/relu.
//
// ws: [0,256KB) counts | [256KB,+4MB) h2 | cols u16 (6.3MB) | lrows u8 (3.1MB)

constexpr int NN   = 16384;
constexpr int D    = 128;
constexpr int NB   = 512;            // buckets
constexpr int RPB  = 32;             // rows per bucket
constexpr int WPR  = NN / 32;        // 512 mask words per row
constexpr int EPB  = 4096;           // edges per partition block
constexpr int NPART = 128;           // partition blocks (E/EPB)
constexpr int SLOT = 48;             // slots per (bucket, pblock) segment
constexpr int LCAP = 320;            // per-wave neighbor list capacity

constexpr size_t H2_OFF  = 262144;                            // counts: 256 KB
constexpr size_t COL_OFF = H2_OFF + (size_t)NN * 64 * 4;      // h2: 4 MB
constexpr size_t LR_OFF  = COL_OFF + (size_t)NPART * NB * SLOT * 2;

typedef short short8 __attribute__((ext_vector_type(8)));     // 8 bf16
typedef float f32x4  __attribute__((ext_vector_type(4)));     // C/D frag

__device__ inline unsigned short f2bf(float f) {
    union { float f; unsigned int u; } x; x.f = f;
    unsigned int u = x.u;
    unsigned int r = (u + 0x7fffu + ((u >> 16) & 1u)) >> 16;   // RTNE
    return (unsigned short)r;
}

// ---------------- fused: partition (blocks [0,NPART)) + gemm (rest) -------
__global__ __launch_bounds__(256) void part_gemm_kernel(
    const int* __restrict__ ei, int E,
    unsigned int* __restrict__ counts,
    unsigned short* __restrict__ cols_g, unsigned char* __restrict__ lr_g,
    const float* __restrict__ x, const float* __restrict__ w,
    unsigned short* __restrict__ h2s) {
    // partition: loff 2KB | staged_col 48KB | staged_lr 24KB  (74 KB)
    // gemm: first 32 KB (x tile 16K + wT tile 16K)
    __shared__ __align__(16) char smem[75776];
    const int tid = threadIdx.x;

    if ((int)blockIdx.x < NPART) {
        // ------------- partition: LDS staging, coalesced flush ------------
        int* loff = (int*)smem;                                   // [512]
        unsigned short* scol = (unsigned short*)(smem + 2048);    // [NB*SLOT]
        unsigned char*  slr  = (unsigned char*)(smem + 51200);    // [NB*SLOT]
        for (int i = tid; i < NB; i += 256) loff[i] = 0;
        __syncthreads();

        const int e0 = blockIdx.x * EPB;
        const int pb = blockIdx.x;
        #pragma unroll
        for (int k = 0; k < 16; ++k) {
            int p = e0 + k * 256 + tid;
            if (p < E) {
                int u = ei[p];
                int v = ei[E + p];
                int b1 = u >> 5;
                int o1 = atomicAdd(&loff[b1], 1);
                if (o1 < SLOT) {
                    scol[b1 * SLOT + o1] = (unsigned short)v;
                    slr [b1 * SLOT + o1] = (unsigned char)(u & 31);
                }
                int b2 = v >> 5;
                int o2 = atomicAdd(&loff[b2], 1);
                if (o2 < SLOT) {
                    scol[b2 * SLOT + o2] = (unsigned short)u;
                    slr [b2 * SLOT + o2] = (unsigned char)(v & 31);
                }
            }
        }
        __syncthreads();
        for (int b = tid; b < NB; b += 256) {
            int c = loff[b]; if (c > SLOT) c = SLOT;
            counts[(size_t)b * NPART + pb] = (unsigned)c;
        }
        // burst flush: whole staged region, fully contiguous + coalesced.
        // garbage in unused slots is fine (counts clamp reads).
        {
            const uint4* src = (const uint4*)scol;                 // 3072 uint4
            uint4* dst = (uint4*)(cols_g + (size_t)pb * NB * SLOT);
            #pragma unroll
            for (int k = 0; k < 12; ++k) dst[tid + k * 256] = src[tid + k * 256];
            const uint4* src2 = (const uint4*)slr;                 // 1536 uint4
            uint4* dst2 = (uint4*)(lr_g + (size_t)pb * NB * SLOT);
            #pragma unroll
            for (int k = 0; k < 6; ++k) dst2[tid + k * 256] = src2[tid + k * 256];
        }
        return;
    }

    // ------------- gemm: 64x64 tile via mfma_f32_16x16x32_bf16 ------------
    const int gb   = (int)blockIdx.x - NPART;
    const int rb   = gb >> 1, cb = gb & 1;
    const int row0 = rb * 64, col0 = cb * 64;

    // stage x tile -> bf16, 16B-granule XOR swizzle (g ^= r&7)
    #pragma unroll
    for (int j = 0; j < 8; ++j) {
        int f  = tid + j * 256;
        int r  = f >> 5, c4 = f & 31;
        float4 xv = *(const float4*)&x[(size_t)(row0 + r) * D + (c4 << 2)];
        unsigned int lo = (unsigned)f2bf(xv.x) | ((unsigned)f2bf(xv.y) << 16);
        unsigned int hi = (unsigned)f2bf(xv.z) | ((unsigned)f2bf(xv.w) << 16);
        int g = c4 >> 1;
        int byte = r * 256 + ((g ^ (r & 7)) << 4) + ((c4 & 1) << 3);
        uint2 p; p.x = lo; p.y = hi;
        *(uint2*)&smem[byte] = p;
    }
    // stage W tile transposed -> wT[col][k] bf16, same swizzle
    #pragma unroll
    for (int j = 0; j < 8; ++j) {
        int f  = tid + j * 256;
        int k  = f >> 4, c4 = f & 15;
        float4 wv = *(const float4*)&w[(size_t)k * D + col0 + (c4 << 2)];
        const float vals[4] = {wv.x, wv.y, wv.z, wv.w};
        #pragma unroll
        for (int i = 0; i < 4; ++i) {
            int c = (c4 << 2) + i;
            int byte = 16384 + c * 256 + (((k >> 3) ^ (c & 7)) << 4) + ((k & 7) << 1);
            *(unsigned short*)&smem[byte] = f2bf(vals[i]);
        }
    }
    __syncthreads();

    const int lane = tid & 63, wave = tid >> 6;
    const int wr = wave >> 1, wc = wave & 1;
    const int l15 = lane & 15, l4 = lane >> 4;

    f32x4 acc[2][2] = {};
    #pragma unroll
    for (int kk = 0; kk < 4; ++kk) {
        int g = (kk << 2) + l4;
        short8 a[2], b[2];
        #pragma unroll
        for (int mi = 0; mi < 2; ++mi) {
            int r = wr * 32 + mi * 16 + l15;
            a[mi] = *(short8*)&smem[r * 256 + ((g ^ (r & 7)) << 4)];
        }
        #pragma unroll
        for (int ni = 0; ni < 2; ++ni) {
            int c = wc * 32 + ni * 16 + l15;
            b[ni] = *(short8*)&smem[16384 + c * 256 + ((g ^ (c & 7)) << 4)];
        }
        #pragma unroll
        for (int mi = 0; mi < 2; ++mi)
            #pragma unroll
            for (int ni = 0; ni < 2; ++ni)
                acc[mi][ni] = __builtin_amdgcn_mfma_f32_16x16x32_bf16(
                    a[mi], b[ni], acc[mi][ni], 0, 0, 0);
    }

    // epilogue: C/D layout col=lane&15, row=(lane>>4)*4+reg (m89-verified)
    #pragma unroll
    for (int mi = 0; mi < 2; ++mi)
        #pragma unroll
        for (int ni = 0; ni < 2; ++ni) {
            int col = col0 + wc * 32 + ni * 16 + l15;
            #pragma unroll
            for (int reg = 0; reg < 4; ++reg) {
                int row = row0 + wr * 32 + mi * 16 + (l4 << 2) + reg;
                h2s[(size_t)row * D + col] = f2bf(acc[mi][ni][reg]);
            }
        }
}

// ---------------- agg: one block per bucket ----------------
__global__ __launch_bounds__(512) void agg_kernel(
    const unsigned int* __restrict__ counts,
    const unsigned short* __restrict__ cols_g,
    const unsigned char* __restrict__ lr_g,
    const unsigned int* __restrict__ h2, float* __restrict__ out) {
    __shared__ unsigned int mask[RPB * WPR];   // 64 KB: 32 rows x 16384 bits
    __shared__ int cnt_s[NPART];
    __shared__ int Lw[8][LCAP];                // 10 KB per-wave lists
    const int b = blockIdx.x, tid = threadIdx.x;
    const int wave = tid >> 6, lane = tid & 63;

    {   // vectorized zero: 4096 uint4 / 512 threads = 8 each
        uint4* m4 = (uint4*)mask;
        uint4 z; z.x = z.y = z.z = z.w = 0u;
        #pragma unroll
        for (int k = 0; k < 8; ++k) m4[tid + k * 512] = z;
    }
    if (tid < NPART) {
        int c = (int)counts[(size_t)b * NPART + tid];
        if (c > SLOT) c = SLOT;
        cnt_s[tid] = c;
    }
    __syncthreads();

    // replay segments: wave w handles segments [16w, 16w+16)
    for (int s = wave * 16; s < wave * 16 + 16; ++s) {
        int c = cnt_s[s];
        if (lane < c) {
            size_t base = ((size_t)s * NB + b) * SLOT + lane;
            unsigned int cc = cols_g[base];
            unsigned int lr = lr_g[base];
            atomicOr(&mask[lr * WPR + (cc >> 5)], 1u << (cc & 31u));
        }
    }
    __syncthreads();

    const int r0 = b * RPB;
    for (int rr = wave; rr < RPB; rr += 8) {
        const unsigned int* mrow = &mask[rr * WPR];
        unsigned int wbits[8];
        int c = 0;
        #pragma unroll
        for (int k = 0; k < 8; ++k) {          // stride-64 words: conflict-free
            wbits[k] = mrow[lane + k * 64];
            c += __popc(wbits[k]);
        }
        int inc = c;
        #pragma unroll
        for (int dd = 1; dd < 64; dd <<= 1) {
            int t = __shfl_up(inc, dd);
            if (lane >= dd) inc += t;
        }
        int p = inc - c;                        // exclusive prefix
        int total = __shfl(inc, 63);
        if (total > LCAP) total = LCAP;
        int* L = Lw[wave];
        #pragma unroll
        for (int k = 0; k < 8; ++k) {
            unsigned int m = wbits[k];
            int cbase = (lane + k * 64) << 5;
            while (m) {
                int bt = __builtin_ctz(m);
                m &= m - 1;
                if (p < LCAP) L[p] = cbase + bt;
                ++p;
            }
        }
        asm volatile("s_waitcnt lgkmcnt(0)" ::: "memory");  // wave-lockstep LDS

        float a0 = 0.f, a1 = 0.f;
        int i = 0;
        for (; i + 8 <= total; i += 8) {
            unsigned int u0 = h2[(unsigned)L[i + 0] * 64u + lane];
            unsigned int u1 = h2[(unsigned)L[i + 1] * 64u + lane];
            unsigned int u2 = h2[(unsigned)L[i + 2] * 64u + lane];
            unsigned int u3 = h2[(unsigned)L[i + 3] * 64u + lane];
            unsigned int u4 = h2[(unsigned)L[i + 4] * 64u + lane];
            unsigned int u5 = h2[(unsigned)L[i + 5] * 64u + lane];
            unsigned int u6 = h2[(unsigned)L[i + 6] * 64u + lane];
            unsigned int u7 = h2[(unsigned)L[i + 7] * 64u + lane];
            a0 += __uint_as_float(u0 << 16); a1 += __uint_as_float(u0 & 0xffff0000u);
            a0 += __uint_as_float(u1 << 16); a1 += __uint_as_float(u1 & 0xffff0000u);
            a0 += __uint_as_float(u2 << 16); a1 += __uint_as_float(u2 & 0xffff0000u);
            a0 += __uint_as_float(u3 << 16); a1 += __uint_as_float(u3 & 0xffff0000u);
            a0 += __uint_as_float(u4 << 16); a1 += __uint_as_float(u4 & 0xffff0000u);
            a0 += __uint_as_float(u5 << 16); a1 += __uint_as_float(u5 & 0xffff0000u);
            a0 += __uint_as_float(u6 << 16); a1 += __uint_as_float(u6 & 0xffff0000u);
            a0 += __uint_as_float(u7 << 16); a1 += __uint_as_float(u7 & 0xffff0000u);
        }
        for (; i < total; ++i) {
            unsigned int u0 = h2[(unsigned)L[i] * 64u + lane];
            a0 += __uint_as_float(u0 << 16); a1 += __uint_as_float(u0 & 0xffff0000u);
        }
        float2 r; r.x = fmaxf(a0, 0.f); r.y = fmaxf(a1, 0.f);
        *(float2*)&out[(size_t)(r0 + rr) * D + lane * 2] = r;
    }
}

extern "C" void kernel_launch(void* const* d_in, const int* in_sizes, int n_in,
                              void* d_out, int out_size, void* d_ws, size_t ws_size,
                              hipStream_t stream) {
    const float* x  = (const float*)d_in[0];
    const int*   ei = (const int*)d_in[1];     // (2,E) int32
    const float* w  = (const float*)d_in[3];   // d_in[2] = num_nodes scalar
    float* out = (float*)d_out;

    unsigned int*   counts = (unsigned int*)d_ws;
    unsigned short* h2s    = (unsigned short*)((char*)d_ws + H2_OFF);
    unsigned int*   h2     = (unsigned int*)((char*)d_ws + H2_OFF);
    unsigned short* cols_g = (unsigned short*)((char*)d_ws + COL_OFF);
    unsigned char*  lr_g   = (unsigned char*)((char*)d_ws + LR_OFF);

    const int E = in_sizes[1] / 2;

    part_gemm_kernel<<<NPART + 512, 256, 0, stream>>>(
        ei, E, counts, cols_g, lr_g, x, w, h2s);
    agg_kernel<<<NB, 512, 0, stream>>>(counts, cols_g, lr_g, h2, out);
}